// Round 16
// baseline (664.043 us; speedup 1.0000x reference)
//
#include <hip/hip_runtime.h>
#include <hip/hip_cooperative_groups.h>
#include <stdint.h>

// ---------------------------------------------------------------------------
// Conv-SNN, 100 steps, B=64, BETA=0.
// Round 16: single cooperative mega-kernel (9 stages, 8 grid.sync()) to kill
// ~90us of launch overhead, + conv2 B-fragment LDS staging (per-pos 8KB slice
// block-cooperatively loaded; r15 showed conv2 latency-bound on L2 frag
// loads: FETCH 3.7MB, MfmaUtil 34%). Standalone-kernel fallback if the
// cooperative launch is rejected. Math bit-identical to r15 (absmax 0.0).
// ---------------------------------------------------------------------------

namespace cg = cooperative_groups;

#define NSTEPS 100
#define NB 64
#define CAPF1 524288u
#define CAPF2 262144u

typedef short bf16x8 __attribute__((ext_vector_type(8)));
typedef float f32x4 __attribute__((ext_vector_type(4)));

struct Ptrs {
  double *W1R, *W2R;
  uint16_t *WB1, *WB2;
  float *EPS;
  uint32_t *cnt, *rowm, *A1w, *B1w, *mask1, *A2w, *B2w;
  uint64_t *mask2;
  float *cur3;
  uint32_t *list1, *list2;
};

__device__ __forceinline__ Ptrs mk(void* wsv) {
  unsigned char* ws = (unsigned char*)wsv;
  Ptrs p;
  p.W1R   = (double*)(ws + 0);
  p.W2R   = (double*)(ws + 27648);
  p.WB1   = (uint16_t*)(ws + 617472);
  p.WB2   = (uint16_t*)(ws + 650240);
  p.EPS   = (float*)(ws + 945152);
  p.cnt   = (uint32_t*)(ws + 945536);
  p.rowm  = (uint32_t*)(ws + 945664);
  p.A1w   = (uint32_t*)(ws + 3403264);
  p.B1w   = (uint32_t*)(ws + 8420864);
  p.mask1 = (uint32_t*)(ws + 13438464);
  p.A2w   = (uint32_t*)(ws + 18456064);
  p.B2w   = (uint32_t*)(ws + 19736064);
  p.mask2 = (uint64_t*)(ws + 21016064);
  p.cur3  = (float*)(ws + 22296064);
  p.list1 = (uint32_t*)(ws + 22552064);
  p.list2 = (uint32_t*)(ws + 24649216);
  return p;
}

__device__ __forceinline__ uint32_t rotl32(uint32_t v, uint32_t r) {
  return (v << r) | (v >> (32u - r));
}

__device__ __forceinline__ void threefry2x32(uint32_t k0, uint32_t k1,
                                             uint32_t& x0, uint32_t& x1) {
  uint32_t k2 = k0 ^ k1 ^ 0x1BD11BDAu;
  x0 += k0; x1 += k1;
#define TF_R(r) { x0 += x1; x1 = rotl32(x1, r); x1 ^= x0; }
  TF_R(13u) TF_R(15u) TF_R(26u) TF_R(6u)
  x0 += k1; x1 += k2 + 1u;
  TF_R(17u) TF_R(29u) TF_R(16u) TF_R(24u)
  x0 += k2; x1 += k0 + 2u;
  TF_R(13u) TF_R(15u) TF_R(26u) TF_R(6u)
  x0 += k0; x1 += k1 + 3u;
  TF_R(17u) TF_R(29u) TF_R(16u) TF_R(24u)
  x0 += k1; x1 += k2 + 4u;
  TF_R(13u) TF_R(15u) TF_R(26u) TF_R(6u)
  x0 += k2; x1 += k0 + 5u;
#undef TF_R
}

__device__ __forceinline__ double fold_pool_w(const float* W, int base, int pos) {
  int iy = pos / 6, ix = pos % 6;
  double w = 0.0;
  for (int dy = 0; dy < 2; ++dy) {
    int ky = iy - dy; if (ky < 0 || ky > 4) continue;
    for (int dx = 0; dx < 2; ++dx) {
      int kx = ix - dx; if (kx < 0 || kx > 4) continue;
      w += (double)W[base + ky * 5 + kx];
    }
  }
  return w;
}

__device__ __forceinline__ uint16_t f2bf(float x) {
  uint32_t u = __float_as_uint(x);
  uint32_t r = (u + 0x7fffu + ((u >> 16) & 1u)) >> 16;
  return (uint16_t)r;
}

// --- stage 0: weights + eps + cnt-zero + spike gen -------------------------
__device__ void st_prep(int v, const float* W_in, const float* W_h1,
                        const float* x, const Ptrs& P) {
  if (v >= 678) {
    int id = (v - 678) * 4 + (threadIdx.x >> 6);
    int lane = threadIdx.x & 63;
    int rp = id & 15, c = (id >> 4) % 3, tb = id / 48;
    int pix = rp * 64 + lane;
    int b = tb & 63;
    uint32_t i = (uint32_t)((tb * 3 + c) * 1024 + pix);
    uint32_t x0 = 0u, x1 = i;
    threefry2x32(0u, 1u, x0, x1);
    uint32_t bits = x0 ^ x1;
    float u = __uint_as_float((bits >> 9) | 0x3f800000u) - 1.0f;
    float xv = x[(b * 3 + c) * 1024 + pix];
    unsigned long long mask = __ballot(u < 2.0f * xv);
    if (lane == 0) ((unsigned long long*)P.rowm)[id] = mask;
    return;
  }
  if (v < 654) {
    int e = v * 256 + threadIdx.x;
    if (e < 3456) {
      int oj = e & 7, c = (e >> 3) % 3, pos = ((e >> 3) / 3) % 36, og = (e >> 3) / 108;
      int oc = og * 8 + oj;
      P.W1R[e] = fold_pool_w(W_in, (oc * 3 + c) * 25, pos);
    } else if (e < 77184) {
      int e2 = e - 3456;
      int oj = e2 & 15, pos = (e2 >> 4) % 36, c = ((e2 >> 4) / 36) % 32, og = e2 / 18432;
      int oc = og * 16 + oj;
      P.W2R[e2] = fold_pool_w(W_h1, (oc * 32 + c) * 25, pos);
    } else if (e < 93568) {
      int e3 = e - 77184;
      int j = e3 & 7, lane = (e3 >> 3) & 63, nt = (e3 >> 9) & 1, ks = (e3 >> 10) & 3, hl = e3 >> 12;
      int k = ks * 32 + (lane >> 4) * 8 + j;
      int oc = nt * 16 + (lane & 15);
      uint16_t val = 0;
      if (k < 108) {
        int c = k / 36, pos = k % 36;
        double w = fold_pool_w(W_in, (oc * 3 + c) * 25, pos);
        uint16_t hi = f2bf((float)w);
        if (hl == 0) val = hi;
        else {
          float hif = __uint_as_float(((uint32_t)hi) << 16);
          val = f2bf((float)(w - (double)hif));
        }
      }
      P.WB1[e3] = val;
    } else if (e < 167296) {
      int e4 = e - 93568;
      int j = e4 & 7, lane = (e4 >> 3) & 63, nt = (e4 >> 9) & 3, pos = e4 >> 11;
      int oc = nt * 16 + (lane & 15);
      int c  = (lane >> 4) * 8 + j;
      double w = fold_pool_w(W_h1, (oc * 32 + c) * 25, pos);
      uint16_t hi = f2bf((float)w);
      float hif = __uint_as_float(((uint32_t)hi) << 16);
      uint16_t lo = f2bf((float)(w - (double)hif));
      P.WB2[e4] = hi;
      P.WB2[73728 + e4] = lo;
    } else if (e < 167298) {
      P.cnt[e - 167296] = 0;
    }
  } else {
    int wid = threadIdx.x >> 6, lane = threadIdx.x & 63;
    int o = (v - 654) * 4 + wid;
    const double u24 = 5.9604644775390625e-08;
    double s = 0.0;
    if (o < 32) {
      for (int t = lane; t < 108; t += 64) {
        int pos = t / 3, c = t % 3;
        s += fabs(fold_pool_w(W_in, (o * 3 + c) * 25, pos));
      }
    } else {
      int oc = o - 32;
      for (int t = lane; t < 1152; t += 64) {
        int c = t / 36, pos = t % 36;
        s += fabs(fold_pool_w(W_h1, (oc * 32 + c) * 25, pos));
      }
    }
    #pragma unroll
    for (int off = 32; off > 0; off >>= 1) s += __shfl_xor(s, off);
    if (lane == 0)
      P.EPS[o] = (o < 32) ? (float)(s * (108.0 * u24 * 6.0) * 0.25)
                          : (float)(s * (1152.0 * u24 * 6.0) * 0.25);
  }
}

// --- stage 1: conv1 via MFMA ----------------------------------------------
__device__ void st_conv1(int g, const Ptrs& P, uint32_t* sR /*[4*96]*/) {
  uint32_t* cnt = P.cnt;
  uint32_t* list1 = P.list1;
  const int tid = threadIdx.x;
  const int wid = tid >> 6, lane = tid & 63;
  const int tb = g * 4 + wid;
  const int q = lane >> 4, ln = lane & 15;

  for (int i = lane; i < 96; i += 64) sR[wid * 96 + i] = P.rowm[tb * 96 + i];

  const float eps0 = P.EPS[ln];
  const float eps1 = P.EPS[16 + ln];

  bf16x8 bf[2][4][2];
  #pragma unroll
  for (int hl = 0; hl < 2; ++hl)
    #pragma unroll
    for (int ks = 0; ks < 4; ++ks)
      #pragma unroll
      for (int nt = 0; nt < 2; ++nt)
        bf[hl][ks][nt] =
            *(const bf16x8*)(P.WB1 + ((((hl * 4 + ks) * 2 + nt) * 64 + lane) * 8));

  const int wl = lane;
  const int qq = wl >> 2, rr = wl & 3;

  for (int mt = 0; mt < 13; ++mt) {
    int p = mt * 16 + ln;
    int pc = p < 196 ? p : 195;
    int oh = pc / 14, ow = pc % 14;
    uint64_t seg0 = 0, seg1 = 0, seg2 = 0;
    #pragma unroll
    for (int iy = 0; iy < 6; ++iy) {
      seg0 |= (uint64_t)((sR[wid * 96 + 0 * 32 + 2 * oh + iy] >> (2 * ow)) & 0x3fu) << (6 * iy);
      seg1 |= (uint64_t)((sR[wid * 96 + 1 * 32 + 2 * oh + iy] >> (2 * ow)) & 0x3fu) << (6 * iy);
      seg2 |= (uint64_t)((sR[wid * 96 + 2 * 32 + 2 * oh + iy] >> (2 * ow)) & 0x3fu) << (6 * iy);
    }
    uint64_t lo = seg0 | (seg1 << 36);
    uint64_t hi = (seg1 >> 28) | (seg2 << 8);
    uint32_t wz[4] = {(uint32_t)lo, (uint32_t)(lo >> 32),
                      (uint32_t)hi, (uint32_t)(hi >> 32)};

    f32x4 acc0 = (f32x4)(0.0f), acc1 = (f32x4)(0.0f);
    #pragma unroll
    for (int ks = 0; ks < 4; ++ks) {
      uint32_t byte = (wz[ks] >> (q * 8)) & 0xffu;
      union { uint32_t u[4]; bf16x8 v; } a;
      #pragma unroll
      for (int i = 0; i < 4; ++i)
        a.u[i] = (((byte >> (2 * i)) & 1u) ? 0x3F80u : 0u) |
                 (((byte >> (2 * i + 1)) & 1u) ? 0x3F800000u : 0u);
      acc0 = __builtin_amdgcn_mfma_f32_16x16x32_bf16(a.v, bf[0][ks][0], acc0, 0, 0, 0);
      acc0 = __builtin_amdgcn_mfma_f32_16x16x32_bf16(a.v, bf[1][ks][0], acc0, 0, 0, 0);
      acc1 = __builtin_amdgcn_mfma_f32_16x16x32_bf16(a.v, bf[0][ks][1], acc1, 0, 0, 0);
      acc1 = __builtin_amdgcn_mfma_f32_16x16x32_bf16(a.v, bf[1][ks][1], acc1, 0, 0, 0);
    }

    unsigned long long bA0[4], bA1[4], bB0[4], bB1[4], bF0[4], bF1[4];
    #pragma unroll
    for (int r = 0; r < 4; ++r) {
      float c0 = acc0[r] * 0.25f;
      float c1 = acc1[r] * 0.25f;
      bA0[r] = __ballot(c0 > 1.0f);
      bB0[r] = __ballot(c0 > 2.0f);
      bF0[r] = __ballot(fabsf(c0 - 1.0f) <= eps0 || fabsf(c0 - 2.0f) <= eps0);
      bA1[r] = __ballot(c1 > 1.0f);
      bB1[r] = __ballot(c1 > 2.0f);
      bF1[r] = __ballot(fabsf(c1 - 1.0f) <= eps1 || fabsf(c1 - 2.0f) <= eps1);
    }

    int pw = mt * 16 + wl;
    if (wl < 16 && pw < 196) {
#define SEL(B) (rr == 0 ? B[0] : rr == 1 ? B[1] : rr == 2 ? B[2] : B[3])
      uint32_t wA = (uint32_t)((SEL(bA0) >> (qq * 16)) & 0xffffull) |
                    ((uint32_t)((SEL(bA1) >> (qq * 16)) & 0xffffull) << 16);
      uint32_t wB = (uint32_t)((SEL(bB0) >> (qq * 16)) & 0xffffull) |
                    ((uint32_t)((SEL(bB1) >> (qq * 16)) & 0xffffull) << 16);
      uint32_t wF = (uint32_t)((SEL(bF0) >> (qq * 16)) & 0xffffull) |
                    ((uint32_t)((SEL(bF1) >> (qq * 16)) & 0xffffull) << 16);
#undef SEL
      uint32_t idx = (uint32_t)(tb * 196 + pw);
      P.A1w[idx] = wA;
      P.B1w[idx] = wB;
      if (wF) {
        uint32_t n = (uint32_t)__popc(wF);
        uint32_t slot = atomicAdd(&cnt[0], n);
        uint32_t base = idx * 32u;
        while (wF) {
          int bit = __ffs(wF) - 1; wF &= wF - 1;
          if (slot < CAPF1) list1[slot] = base + (uint32_t)bit;
          ++slot;
        }
      }
    }
  }
}

// --- stage 2: fix1 (8-lane teams, grid-stride) ----------------------------
__device__ void st_fix1(const Ptrs& P) {
  uint32_t total = P.cnt[0]; if (total > CAPF1) total = CAPF1;
  const uint32_t g = blockIdx.x * 32 + (threadIdx.x >> 3);
  const int l = threadIdx.x & 7;
  const uint32_t gstride = gridDim.x * 32;
  for (uint32_t i = g; i < total; i += gstride) {
    uint32_t e = P.list1[i];
    uint32_t x = e >> 5;
    int oc = (int)(e & 31u);
    int tb = (int)(x / 196), p = (int)(x % 196);
    int oh = p / 14, ow = p % 14;
    int og = oc >> 3, oj = oc & 7;
    const uint32_t* R = P.rowm + (size_t)tb * 96;
    double acc = 0.0;
    for (int t = l; t < 108; t += 8) {
      int pos = t / 3, c = t - pos * 3;
      int iy = pos / 6, ix = pos - iy * 6;
      double bd = (double)((R[c * 32 + 2 * oh + iy] >> (2 * ow + ix)) & 1u);
      acc = fma(bd, P.W1R[og * 864 + pos * 24 + c * 8 + oj], acc);
    }
    acc += __shfl_xor(acc, 1);
    acc += __shfl_xor(acc, 2);
    acc += __shfl_xor(acc, 4);
    if (l == 0) {
      float cur = (float)(acc * 0.25);
      uint32_t m = 1u << oc;
      if (cur > 1.0f) atomicOr(&P.A1w[x], m); else atomicAnd(&P.A1w[x], ~m);
      if (cur > 2.0f) atomicOr(&P.B1w[x], m); else atomicAnd(&P.B1w[x], ~m);
    }
  }
}

// --- stage 3: LIF1 scan ----------------------------------------------------
__device__ void st_scan1(int v, const Ptrs& P) {
  int chain = v * 256 + threadIdx.x;
  if (chain >= NB * 196) return;
  int b = chain / 196, p = chain % 196;
  const size_t stride = (size_t)NB * 196;
  size_t base = (size_t)b * 196 + p;
  uint32_t prev = 0;
  #pragma unroll
  for (int seg = 0; seg < 4; ++seg) {
    uint32_t Abuf[25], Bbuf[25];
    size_t sb = base + (size_t)(seg * 25) * stride;
    #pragma unroll
    for (int i = 0; i < 25; ++i) {
      Abuf[i] = P.A1w[sb + i * stride];
      Bbuf[i] = P.B1w[sb + i * stride];
    }
    #pragma unroll
    for (int i = 0; i < 25; ++i) {
      uint32_t s = (Abuf[i] & ~prev) | (Bbuf[i] & prev);
      P.mask1[sb + i * stride] = s;
      prev = s;
    }
  }
}

// --- stage 4: conv2 via MFMA, LDS-staged B frags --------------------------
#define CONV2_EPILOG(ACC, TBV)                                                \
  {                                                                           \
    const int w = lane;                                                       \
    const int pw = w >> 1, hfw = w & 1;                                       \
    _Pragma("unroll")                                                         \
    for (int mt2 = 0; mt2 < 2; ++mt2) {                                       \
      const int pt = pw - mt2 * 16;                                           \
      const bool wvalid = (w < 50) && (pt >= 0) && (pt < 16) && (pw < 25);    \
      const int qw = (pt & 15) >> 2, rw = pt & 3;                             \
      uint32_t wA = 0, wB = 0, wF = 0;                                        \
      _Pragma("unroll")                                                       \
      for (int nt = 0; nt < 4; ++nt) {                                        \
        unsigned long long bA[4], bB[4], bF[4];                               \
        _Pragma("unroll")                                                     \
        for (int reg = 0; reg < 4; ++reg) {                                   \
          float c = ACC[mt2 * 4 + nt][reg] * 0.25f;                           \
          float e = epsv[nt];                                                 \
          bA[reg] = __ballot(c > 1.0f);                                       \
          bB[reg] = __ballot(c > 2.0f);                                       \
          bF[reg] = __ballot(fabsf(c - 1.0f) <= e || fabsf(c - 2.0f) <= e);   \
        }                                                                     \
        if (wvalid && (nt >> 1) == hfw) {                                     \
          const int sh = (nt & 1) * 16;                                       \
          unsigned long long sA = rw == 0 ? bA[0] : rw == 1 ? bA[1] : rw == 2 ? bA[2] : bA[3]; \
          unsigned long long sB = rw == 0 ? bB[0] : rw == 1 ? bB[1] : rw == 2 ? bB[2] : bB[3]; \
          unsigned long long sF = rw == 0 ? bF[0] : rw == 1 ? bF[1] : rw == 2 ? bF[2] : bF[3]; \
          wA |= (uint32_t)((sA >> (qw * 16)) & 0xffffull) << sh;              \
          wB |= (uint32_t)((sB >> (qw * 16)) & 0xffffull) << sh;              \
          wF |= (uint32_t)((sF >> (qw * 16)) & 0xffffull) << sh;              \
        }                                                                     \
      }                                                                       \
      if (wvalid) {                                                           \
        uint32_t idx = (uint32_t)((TBV) * 25 + pw) * 2 + hfw;                 \
        P.A2w[idx] = wA;                                                      \
        P.B2w[idx] = wB;                                                      \
        if (wF) {                                                             \
          uint32_t n = (uint32_t)__popc(wF);                                  \
          uint32_t slot = atomicAdd(&P.cnt[1], n);                            \
          uint32_t base2 = idx * 32u;                                         \
          while (wF) {                                                        \
            int bit = __ffs(wF) - 1; wF &= wF - 1;                            \
            if (slot < CAPF2) P.list2[slot] = base2 + (uint32_t)bit;          \
            ++slot;                                                           \
          }                                                                   \
        }                                                                     \
      }                                                                       \
    }                                                                         \
  }

__device__ void st_conv2(int g, const Ptrs& P, uint32_t* sM /*8*196*/,
                         uint16_t* sWB /*4096 u16*/) {
  const int tid = threadIdx.x;
  const int wid = tid >> 6, lane = tid & 63;
  const int tb0 = g * 8 + wid * 2;

  for (int i = lane; i < 392; i += 64)
    sM[wid * 392 + i] = P.mask1[(size_t)tb0 * 196 + i];
  // sM is wave-local; sWB barriers below also order it.

  const int q  = lane >> 4;
  const int ln = lane & 15;
  float epsv[4];
  #pragma unroll
  for (int nt = 0; nt < 4; ++nt) epsv[nt] = P.EPS[32 + nt * 16 + ln];

  const int p0 = ln;
  const int p1 = 16 + ln;
  const bool v1 = (p1 < 25);
  const int oh0 = p0 / 5, ow0 = p0 % 5;
  const int p1c = v1 ? p1 : 0;
  const int oh1 = p1c / 5, ow1 = p1c % 5;

  f32x4 accA[8], accB[8];
  #pragma unroll
  for (int i = 0; i < 8; ++i) { accA[i] = (f32x4)(0.0f); accB[i] = (f32x4)(0.0f); }

  const uint32_t* sW0 = &sM[wid * 392];
  const uint32_t* sW1 = sW0 + 196;
  const uint4* wbsrc = (const uint4*)P.WB2;

  for (int iy = 0; iy < 6; ++iy) {
    #pragma unroll
    for (int ix = 0; ix < 6; ++ix) {
      const int pos = iy * 6 + ix;
      __syncthreads();  // all waves done with previous slice
      ((uint4*)sWB)[tid]       = wbsrc[pos * 256 + tid];            // hi plane
      ((uint4*)sWB)[tid + 256] = wbsrc[9216 + pos * 256 + tid];     // lo plane
      __syncthreads();  // slice visible

      const int o0 = (2 * oh0 + iy) * 14 + 2 * ow0 + ix;
      const int o1 = (2 * oh1 + iy) * 14 + 2 * ow1 + ix;
      uint32_t w00 = sW0[o0];
      uint32_t w01 = v1 ? sW0[o1] : 0u;
      uint32_t w10 = sW1[o0];
      uint32_t w11 = v1 ? sW1[o1] : 0u;
      uint32_t b00 = (w00 >> (q * 8)) & 0xffu;
      uint32_t b01 = (w01 >> (q * 8)) & 0xffu;
      uint32_t b10 = (w10 >> (q * 8)) & 0xffu;
      uint32_t b11 = (w11 >> (q * 8)) & 0xffu;
      union { uint32_t u[4]; bf16x8 v; } a00, a01, a10, a11;
      #pragma unroll
      for (int i = 0; i < 4; ++i) {
        a00.u[i] = (((b00 >> (2 * i)) & 1u) ? 0x3F80u : 0u) |
                   (((b00 >> (2 * i + 1)) & 1u) ? 0x3F800000u : 0u);
        a01.u[i] = (((b01 >> (2 * i)) & 1u) ? 0x3F80u : 0u) |
                   (((b01 >> (2 * i + 1)) & 1u) ? 0x3F800000u : 0u);
        a10.u[i] = (((b10 >> (2 * i)) & 1u) ? 0x3F80u : 0u) |
                   (((b10 >> (2 * i + 1)) & 1u) ? 0x3F800000u : 0u);
        a11.u[i] = (((b11 >> (2 * i)) & 1u) ? 0x3F80u : 0u) |
                   (((b11 >> (2 * i + 1)) & 1u) ? 0x3F800000u : 0u);
      }
      #pragma unroll
      for (int nt = 0; nt < 4; ++nt) {
        bf16x8 bhi = *(const bf16x8*)(sWB + (nt * 64 + lane) * 8);
        bf16x8 blo = *(const bf16x8*)(sWB + 2048 + (nt * 64 + lane) * 8);
        accA[nt] = __builtin_amdgcn_mfma_f32_16x16x32_bf16(a00.v, bhi, accA[nt], 0, 0, 0);
        accA[nt] = __builtin_amdgcn_mfma_f32_16x16x32_bf16(a00.v, blo, accA[nt], 0, 0, 0);
        accA[4 + nt] = __builtin_amdgcn_mfma_f32_16x16x32_bf16(a01.v, bhi, accA[4 + nt], 0, 0, 0);
        accA[4 + nt] = __builtin_amdgcn_mfma_f32_16x16x32_bf16(a01.v, blo, accA[4 + nt], 0, 0, 0);
        accB[nt] = __builtin_amdgcn_mfma_f32_16x16x32_bf16(a10.v, bhi, accB[nt], 0, 0, 0);
        accB[nt] = __builtin_amdgcn_mfma_f32_16x16x32_bf16(a10.v, blo, accB[nt], 0, 0, 0);
        accB[4 + nt] = __builtin_amdgcn_mfma_f32_16x16x32_bf16(a11.v, bhi, accB[4 + nt], 0, 0, 0);
        accB[4 + nt] = __builtin_amdgcn_mfma_f32_16x16x32_bf16(a11.v, blo, accB[4 + nt], 0, 0, 0);
      }
    }
  }

  CONV2_EPILOG(accA, tb0)
  CONV2_EPILOG(accB, (tb0 + 1))
}

// --- stage 5: fix2 (16-lane teams, grid-stride) ---------------------------
__device__ void st_fix2(const Ptrs& P) {
  uint32_t total = P.cnt[1]; if (total > CAPF2) total = CAPF2;
  const uint32_t g = blockIdx.x * 16 + (threadIdx.x >> 4);
  const int l = threadIdx.x & 15;
  const uint32_t gstride = gridDim.x * 16;
  for (uint32_t i = g; i < total; i += gstride) {
    uint32_t e = P.list2[i];
    uint32_t wi = e >> 5;
    int bit = (int)(e & 31u);
    uint32_t x = wi >> 1;
    int oc = (int)((wi & 1u) * 32u) + bit;
    int tb = (int)(x / 25), p = (int)(x % 25);
    int oh = p / 5, ow = p % 5;
    int og = oc >> 4, oj = oc & 15;
    const uint32_t* M = P.mask1 + (size_t)tb * 196;
    double acc = 0.0;
    for (int t = l; t < 1152; t += 16) {
      int c = t / 36, pos = t - c * 36;
      int iy = pos / 6, ix = pos - iy * 6;
      uint32_t mm = M[(2 * oh + iy) * 14 + 2 * ow + ix];
      double bd = (double)((mm >> c) & 1u);
      acc = fma(bd, P.W2R[og * 18432 + c * 576 + pos * 16 + oj], acc);
    }
    acc += __shfl_xor(acc, 1);
    acc += __shfl_xor(acc, 2);
    acc += __shfl_xor(acc, 4);
    acc += __shfl_xor(acc, 8);
    if (l == 0) {
      float cur = (float)(acc * 0.25);
      uint32_t m = 1u << bit;
      if (cur > 1.0f) atomicOr(&P.A2w[wi], m); else atomicAnd(&P.A2w[wi], ~m);
      if (cur > 2.0f) atomicOr(&P.B2w[wi], m); else atomicAnd(&P.B2w[wi], ~m);
    }
  }
}

// --- stage 6: LIF2 scan ----------------------------------------------------
__device__ void st_scan2(int v, const Ptrs& P) {
  int chain = v * 256 + threadIdx.x;
  if (chain >= NB * 25) return;
  const uint64_t* A2q = (const uint64_t*)P.A2w;
  const uint64_t* B2q = (const uint64_t*)P.B2w;
  int b = chain / 25, p = chain % 25;
  const size_t stride = (size_t)NB * 25;
  size_t base = (size_t)b * 25 + p;
  uint64_t prev = 0;
  #pragma unroll
  for (int seg = 0; seg < 4; ++seg) {
    uint64_t Abuf[25], Bbuf[25];
    size_t sb = base + (size_t)(seg * 25) * stride;
    #pragma unroll
    for (int i = 0; i < 25; ++i) {
      Abuf[i] = A2q[sb + i * stride];
      Bbuf[i] = B2q[sb + i * stride];
    }
    #pragma unroll
    for (int i = 0; i < 25; ++i) {
      uint64_t s = (Abuf[i] & ~prev) | (Bbuf[i] & prev);
      P.mask2[sb + i * stride] = s;
      prev = s;
    }
  }
}

// --- stage 7: FC (grid-stride) --------------------------------------------
__device__ void st_fc(const Ptrs& P, const float* W2) {
  for (int gid = blockIdx.x * 256 + threadIdx.x; gid < NSTEPS * NB * 80;
       gid += gridDim.x * 256) {
    int tb = gid / 80, r = gid % 80;
    int o = r >> 3, s = r & 7;
    const uint64_t* m = P.mask2 + (size_t)tb * 25;
    const float* w = W2 + o * 1600 + s * 200;
    uint64_t mw[25];
    #pragma unroll
    for (int p = 0; p < 25; ++p) mw[p] = m[p];
    const int oc0 = s * 8;
    double acc0 = 0.0, acc1 = 0.0;
    #pragma unroll
    for (int j = 0; j < 8; ++j) {
      const float* wj = w + j * 25;
      double a = 0.0;
      #pragma unroll
      for (int p = 0; p < 25; ++p) {
        double bd = (double)((mw[p] >> (oc0 + j)) & 1ull);
        a = fma(bd, (double)wj[p], a);
      }
      if (j & 1) acc1 += a; else acc0 += a;
    }
    double acc = acc0 + acc1;
    acc += __shfl_xor(acc, 4);
    acc += __shfl_xor(acc, 2);
    acc += __shfl_xor(acc, 1);
    if (s == 0) P.cur3[tb * 10 + o] = (float)acc;
  }
}

// --- stage 8: LIF3 ---------------------------------------------------------
__device__ void st_lif3(int v, const Ptrs& P, float* out) {
  int bo = v * 256 + threadIdx.x;
  if (bo >= NB * 10) return;
  float prev = 0.0f;
  #pragma unroll
  for (int seg = 0; seg < 4; ++seg) {
    float cbuf[25];
    #pragma unroll
    for (int i = 0; i < 25; ++i) cbuf[i] = P.cur3[(seg * 25 + i) * 640 + bo];
    #pragma unroll
    for (int i = 0; i < 25; ++i) {
      int t = seg * 25 + i;
      float mem = cbuf[i] - prev;
      bool s = mem > 1.0f;
      out[t * 640 + bo] = s ? 1.0f : 0.0f;
      out[NSTEPS * 640 + t * 640 + bo] = mem;
      prev = s ? 1.0f : 0.0f;
    }
  }
}

// --- cooperative mega-kernel ----------------------------------------------
__global__ __launch_bounds__(256, 3) void snn_mega(const float* x, const float* W_in,
                                                   const float* W_h1, const float* W_h2,
                                                   float* out, void* wsv) {
  Ptrs P = mk(wsv);
  cg::grid_group grid = cg::this_grid();
  __shared__ __align__(16) char smem[14464];
  uint32_t* sR  = (uint32_t*)smem;
  uint32_t* sM  = (uint32_t*)smem;
  uint16_t* sWB = (uint16_t*)(smem + 6272);
  const int nb = gridDim.x;

  for (int v = blockIdx.x; v < 678 + 76800; v += nb) st_prep(v, W_in, W_h1, x, P);
  grid.sync();
  for (int g = blockIdx.x; g < 1600; g += nb) st_conv1(g, P, sR);
  grid.sync();
  st_fix1(P);
  grid.sync();
  for (int v = blockIdx.x; v < 49; v += nb) st_scan1(v, P);
  grid.sync();
  for (int g = blockIdx.x; g < 800; g += nb) st_conv2(g, P, sM, sWB);
  grid.sync();
  st_fix2(P);
  grid.sync();
  for (int v = blockIdx.x; v < 7; v += nb) st_scan2(v, P);
  grid.sync();
  st_fc(P, W_h2);
  grid.sync();
  for (int v = blockIdx.x; v < 3; v += nb) st_lif3(v, P, out);
}

// --- standalone fallback kernels ------------------------------------------
__global__ __launch_bounds__(256) void k_prep(const float* x, const float* W_in,
                                              const float* W_h1, void* wsv) {
  Ptrs P = mk(wsv);
  st_prep(blockIdx.x, W_in, W_h1, x, P);
}
__global__ __launch_bounds__(256) void k_conv1(void* wsv) {
  Ptrs P = mk(wsv);
  __shared__ __align__(16) uint32_t sR[4 * 96];
  st_conv1(blockIdx.x, P, sR);
}
__global__ __launch_bounds__(256) void k_fix1(void* wsv) {
  Ptrs P = mk(wsv);
  st_fix1(P);
}
__global__ __launch_bounds__(256) void k_scan1(void* wsv) {
  Ptrs P = mk(wsv);
  st_scan1(blockIdx.x, P);
}
__global__ __launch_bounds__(256, 3) void k_conv2(void* wsv) {
  Ptrs P = mk(wsv);
  __shared__ __align__(16) char smem[14464];
  st_conv2(blockIdx.x, P, (uint32_t*)smem, (uint16_t*)(smem + 6272));
}
__global__ __launch_bounds__(256) void k_fix2(void* wsv) {
  Ptrs P = mk(wsv);
  st_fix2(P);
}
__global__ __launch_bounds__(256) void k_scan2(void* wsv) {
  Ptrs P = mk(wsv);
  st_scan2(blockIdx.x, P);
}
__global__ __launch_bounds__(256) void k_fc(const float* W_h2, void* wsv) {
  Ptrs P = mk(wsv);
  st_fc(P, W_h2);
}
__global__ __launch_bounds__(256) void k_lif3(float* out, void* wsv) {
  Ptrs P = mk(wsv);
  st_lif3(blockIdx.x, P, out);
}

extern "C" void kernel_launch(void* const* d_in, const int* in_sizes, int n_in,
                              void* d_out, int out_size, void* d_ws, size_t ws_size,
                              hipStream_t stream) {
  const float* x    = (const float*)d_in[0];
  const float* W_in = (const float*)d_in[1];
  const float* W_h1 = (const float*)d_in[2];
  const float* W_h2 = (const float*)d_in[3];
  float* out = (float*)d_out;
  void* wsv = d_ws;

  bool coop_ok = false;
  int maxb = 0;
  hipError_t occ = hipOccupancyMaxActiveBlocksPerMultiprocessor(&maxb, snn_mega, 256, (size_t)0);
  if (occ == hipSuccess && maxb >= 1) {
    int nblk = maxb * 256;           // 256 CUs on MI355X
    if (nblk > 2048) nblk = 2048;
    void* args[] = {(void*)&x, (void*)&W_in, (void*)&W_h1, (void*)&W_h2,
                    (void*)&out, (void*)&wsv};
    hipError_t e = hipLaunchCooperativeKernel(snn_mega, dim3(nblk), dim3(256),
                                              args, 0u, stream);
    coop_ok = (e == hipSuccess);
  }
  if (!coop_ok) {
    k_prep<<<678 + 76800, 256, 0, stream>>>(x, W_in, W_h1, wsv);
    k_conv1<<<1600, 256, 0, stream>>>(wsv);
    k_fix1<<<1024, 256, 0, stream>>>(wsv);
    k_scan1<<<49, 256, 0, stream>>>(wsv);
    k_conv2<<<800, 256, 0, stream>>>(wsv);
    k_fix2<<<1024, 256, 0, stream>>>(wsv);
    k_scan2<<<7, 256, 0, stream>>>(wsv);
    k_fc<<<2000, 256, 0, stream>>>(W_h2, wsv);
    k_lif3<<<3, 256, 0, stream>>>(out, wsv);
  }
}

// Round 17
// 288.430 us; speedup vs baseline: 2.3023x; 2.3023x over previous
//
#include <hip/hip_runtime.h>
#include <stdint.h>

// ---------------------------------------------------------------------------
// Conv-SNN, 100 steps, B=64, BETA=0.
// Round 17: REVERT to round-15 pipeline (299us; the r16 cooperative mega-
// kernel collapsed to 3% MfmaUtil — grid.sync + per-pos barriers), then fold
// the f64 fixups INTO the conv epilogues: the producing wave recomputes each
// flagged output cooperatively (64 lanes, shfl_xor reduce) and patches its
// A/B word in registers pre-store. Deletes fix kernels, worklists, cnt,
// atomics: 9 -> 7 launches. f64 lane-split reorder accepted per r9/r15.
// All other kernels byte-identical to round 15 (absmax 0.0 lineage).
// ---------------------------------------------------------------------------

#define NSTEPS 100
#define NB 64

typedef short bf16x8 __attribute__((ext_vector_type(8)));
typedef float f32x4 __attribute__((ext_vector_type(4)));

__device__ __forceinline__ uint32_t rotl32(uint32_t v, uint32_t r) {
  return (v << r) | (v >> (32u - r));
}

__device__ __forceinline__ void threefry2x32(uint32_t k0, uint32_t k1,
                                             uint32_t& x0, uint32_t& x1) {
  uint32_t k2 = k0 ^ k1 ^ 0x1BD11BDAu;
  x0 += k0; x1 += k1;
#define TF_R(r) { x0 += x1; x1 = rotl32(x1, r); x1 ^= x0; }
  TF_R(13u) TF_R(15u) TF_R(26u) TF_R(6u)
  x0 += k1; x1 += k2 + 1u;
  TF_R(17u) TF_R(29u) TF_R(16u) TF_R(24u)
  x0 += k2; x1 += k0 + 2u;
  TF_R(13u) TF_R(15u) TF_R(26u) TF_R(6u)
  x0 += k0; x1 += k1 + 3u;
  TF_R(17u) TF_R(29u) TF_R(16u) TF_R(24u)
  x0 += k1; x1 += k2 + 4u;
  TF_R(13u) TF_R(15u) TF_R(26u) TF_R(6u)
  x0 += k2; x1 += k0 + 5u;
#undef TF_R
}

__device__ __forceinline__ double fold_pool_w(const float* W, int base, int pos) {
  int iy = pos / 6, ix = pos % 6;
  double w = 0.0;
  for (int dy = 0; dy < 2; ++dy) {
    int ky = iy - dy; if (ky < 0 || ky > 4) continue;
    for (int dx = 0; dx < 2; ++dx) {
      int kx = ix - dx; if (kx < 0 || kx > 4) continue;
      w += (double)W[base + ky * 5 + kx];
    }
  }
  return w;
}

__device__ __forceinline__ uint16_t f2bf(float x) {  // RNE bf16
  uint32_t u = __float_as_uint(x);
  uint32_t r = (u + 0x7fffu + ((u >> 16) & 1u)) >> 16;
  return (uint16_t)r;
}

// --- prep_gen: [0,654) weights, [654,678) eps, [678,...) spike gen --------
__global__ __launch_bounds__(256) void prep_gen(const float* __restrict__ W_in,
                                                const float* __restrict__ W_h1,
                                                const float* __restrict__ x,
                                                double* __restrict__ W1R,
                                                double* __restrict__ W2R,
                                                uint16_t* __restrict__ WB1,
                                                uint16_t* __restrict__ WB2,
                                                float* __restrict__ EPS,
                                                uint32_t* __restrict__ rowm) {
  if (blockIdx.x >= 678) {
    int id = (blockIdx.x - 678) * 4 + (threadIdx.x >> 6);
    int lane = threadIdx.x & 63;
    int rp = id & 15, c = (id >> 4) % 3, tb = id / 48;
    int pix = rp * 64 + lane;
    int b = tb & 63;
    uint32_t i = (uint32_t)((tb * 3 + c) * 1024 + pix);
    uint32_t x0 = 0u, x1 = i;
    threefry2x32(0u, 1u, x0, x1);
    uint32_t bits = x0 ^ x1;
    float u = __uint_as_float((bits >> 9) | 0x3f800000u) - 1.0f;
    float xv = x[(b * 3 + c) * 1024 + pix];
    unsigned long long mask = __ballot(u < 2.0f * xv);
    if (lane == 0) ((unsigned long long*)rowm)[id] = mask;
    return;
  }
  if (blockIdx.x < 654) {
    int e = blockIdx.x * 256 + threadIdx.x;
    if (e < 3456) {
      int oj = e & 7, c = (e >> 3) % 3, pos = ((e >> 3) / 3) % 36, og = (e >> 3) / 108;
      int oc = og * 8 + oj;
      W1R[e] = fold_pool_w(W_in, (oc * 3 + c) * 25, pos);
    } else if (e < 77184) {
      int e2 = e - 3456;
      int oj = e2 & 15, pos = (e2 >> 4) % 36, c = ((e2 >> 4) / 36) % 32, og = e2 / 18432;
      int oc = og * 16 + oj;
      W2R[e2] = fold_pool_w(W_h1, (oc * 32 + c) * 25, pos);
    } else if (e < 93568) {
      int e3 = e - 77184;
      int j = e3 & 7, lane = (e3 >> 3) & 63, nt = (e3 >> 9) & 1, ks = (e3 >> 10) & 3, hl = e3 >> 12;
      int k = ks * 32 + (lane >> 4) * 8 + j;
      int oc = nt * 16 + (lane & 15);
      uint16_t val = 0;
      if (k < 108) {
        int c = k / 36, pos = k % 36;
        double w = fold_pool_w(W_in, (oc * 3 + c) * 25, pos);
        uint16_t hi = f2bf((float)w);
        if (hl == 0) val = hi;
        else {
          float hif = __uint_as_float(((uint32_t)hi) << 16);
          val = f2bf((float)(w - (double)hif));
        }
      }
      WB1[e3] = val;
    } else if (e < 167296) {
      int e4 = e - 93568;
      int j = e4 & 7, lane = (e4 >> 3) & 63, nt = (e4 >> 9) & 3, pos = e4 >> 11;
      int oc = nt * 16 + (lane & 15);
      int c  = (lane >> 4) * 8 + j;
      double w = fold_pool_w(W_h1, (oc * 32 + c) * 25, pos);
      uint16_t hi = f2bf((float)w);
      float hif = __uint_as_float(((uint32_t)hi) << 16);
      uint16_t lo = f2bf((float)(w - (double)hif));
      WB2[e4] = hi;
      WB2[73728 + e4] = lo;
    }
  } else {
    int wid = threadIdx.x >> 6, lane = threadIdx.x & 63;
    int o = (blockIdx.x - 654) * 4 + wid;
    const double u24 = 5.9604644775390625e-08;
    double s = 0.0;
    if (o < 32) {
      for (int t = lane; t < 108; t += 64) {
        int pos = t / 3, c = t % 3;
        s += fabs(fold_pool_w(W_in, (o * 3 + c) * 25, pos));
      }
    } else {
      int oc = o - 32;
      for (int t = lane; t < 1152; t += 64) {
        int c = t / 36, pos = t % 36;
        s += fabs(fold_pool_w(W_h1, (oc * 32 + c) * 25, pos));
      }
    }
    #pragma unroll
    for (int off = 32; off > 0; off >>= 1) s += __shfl_xor(s, off);
    if (lane == 0)
      EPS[o] = (o < 32) ? (float)(s * (108.0 * u24 * 6.0) * 0.25)
                        : (float)(s * (1152.0 * u24 * 6.0) * 0.25);
  }
}

// --- conv1 via MFMA + in-epilogue cooperative f64 fix ---------------------
__global__ __launch_bounds__(256) void conv1_mfma(const uint32_t* __restrict__ rowm,
                                                  const uint16_t* __restrict__ WB1,
                                                  const float* __restrict__ EPS,
                                                  const double* __restrict__ W1R,
                                                  uint32_t* __restrict__ A1w,
                                                  uint32_t* __restrict__ B1w) {
  __shared__ uint32_t sR[4][96];
  const int tid = threadIdx.x;
  const int wid = tid >> 6, lane = tid & 63;
  const int tb = blockIdx.x * 4 + wid;
  const int q = lane >> 4, ln = lane & 15;

  for (int i = lane; i < 96; i += 64) sR[wid][i] = rowm[tb * 96 + i];

  const float eps0 = EPS[ln];
  const float eps1 = EPS[16 + ln];

  bf16x8 bf[2][4][2];
  #pragma unroll
  for (int hl = 0; hl < 2; ++hl)
    #pragma unroll
    for (int ks = 0; ks < 4; ++ks)
      #pragma unroll
      for (int nt = 0; nt < 2; ++nt)
        bf[hl][ks][nt] =
            *(const bf16x8*)(WB1 + ((((hl * 4 + ks) * 2 + nt) * 64 + lane) * 8));

  const int wl = lane;
  const int qq = wl >> 2, rr = wl & 3;

  for (int mt = 0; mt < 13; ++mt) {
    int p = mt * 16 + ln;
    int pc = p < 196 ? p : 195;
    int oh = pc / 14, ow = pc % 14;
    uint64_t seg0 = 0, seg1 = 0, seg2 = 0;
    #pragma unroll
    for (int iy = 0; iy < 6; ++iy) {
      seg0 |= (uint64_t)((sR[wid][0 * 32 + 2 * oh + iy] >> (2 * ow)) & 0x3fu) << (6 * iy);
      seg1 |= (uint64_t)((sR[wid][1 * 32 + 2 * oh + iy] >> (2 * ow)) & 0x3fu) << (6 * iy);
      seg2 |= (uint64_t)((sR[wid][2 * 32 + 2 * oh + iy] >> (2 * ow)) & 0x3fu) << (6 * iy);
    }
    uint64_t lo = seg0 | (seg1 << 36);
    uint64_t hi = (seg1 >> 28) | (seg2 << 8);
    uint32_t wz[4] = {(uint32_t)lo, (uint32_t)(lo >> 32),
                      (uint32_t)hi, (uint32_t)(hi >> 32)};

    f32x4 acc0 = (f32x4)(0.0f), acc1 = (f32x4)(0.0f);
    #pragma unroll
    for (int ks = 0; ks < 4; ++ks) {
      uint32_t byte = (wz[ks] >> (q * 8)) & 0xffu;
      union { uint32_t u[4]; bf16x8 v; } a;
      #pragma unroll
      for (int i = 0; i < 4; ++i)
        a.u[i] = (((byte >> (2 * i)) & 1u) ? 0x3F80u : 0u) |
                 (((byte >> (2 * i + 1)) & 1u) ? 0x3F800000u : 0u);
      acc0 = __builtin_amdgcn_mfma_f32_16x16x32_bf16(a.v, bf[0][ks][0], acc0, 0, 0, 0);
      acc0 = __builtin_amdgcn_mfma_f32_16x16x32_bf16(a.v, bf[1][ks][0], acc0, 0, 0, 0);
      acc1 = __builtin_amdgcn_mfma_f32_16x16x32_bf16(a.v, bf[0][ks][1], acc1, 0, 0, 0);
      acc1 = __builtin_amdgcn_mfma_f32_16x16x32_bf16(a.v, bf[1][ks][1], acc1, 0, 0, 0);
    }

    unsigned long long bA0[4], bA1[4], bB0[4], bB1[4], bF0[4], bF1[4];
    #pragma unroll
    for (int r = 0; r < 4; ++r) {
      float c0 = acc0[r] * 0.25f;
      float c1 = acc1[r] * 0.25f;
      bA0[r] = __ballot(c0 > 1.0f);
      bB0[r] = __ballot(c0 > 2.0f);
      bF0[r] = __ballot(fabsf(c0 - 1.0f) <= eps0 || fabsf(c0 - 2.0f) <= eps0);
      bA1[r] = __ballot(c1 > 1.0f);
      bB1[r] = __ballot(c1 > 2.0f);
      bF1[r] = __ballot(fabsf(c1 - 1.0f) <= eps1 || fabsf(c1 - 2.0f) <= eps1);
    }

    int pw = mt * 16 + wl;
    const bool wvalid = (wl < 16 && pw < 196);
    uint32_t wA = 0, wB = 0, wF = 0;
    if (wvalid) {
#define SEL(B) (rr == 0 ? B[0] : rr == 1 ? B[1] : rr == 2 ? B[2] : B[3])
      wA = (uint32_t)((SEL(bA0) >> (qq * 16)) & 0xffffull) |
           ((uint32_t)((SEL(bA1) >> (qq * 16)) & 0xffffull) << 16);
      wB = (uint32_t)((SEL(bB0) >> (qq * 16)) & 0xffffull) |
           ((uint32_t)((SEL(bB1) >> (qq * 16)) & 0xffffull) << 16);
      wF = (uint32_t)((SEL(bF0) >> (qq * 16)) & 0xffffull) |
           ((uint32_t)((SEL(bF1) >> (qq * 16)) & 0xffffull) << 16);
#undef SEL
    }

    // wave-cooperative exact f64 fix of flagged bits (rare)
    unsigned long long flagged = __ballot(wF != 0);
    while (flagged) {
      int src = (int)__ffsll(flagged) - 1;
      uint32_t fsrc = (uint32_t)__shfl((int)wF, src);
      int ocb = __ffs((int)fsrc) - 1;
      int pf = mt * 16 + src;
      int ohf = pf / 14, owf = pf % 14;
      int og = ocb >> 3, oj = ocb & 7;
      double acc = 0.0;
      for (int t = lane; t < 108; t += 64) {   // t = pos*3 + c
        int pos = t / 3, c = t - pos * 3;
        int iy = pos / 6, ix = pos - iy * 6;
        double bd = (double)((sR[wid][c * 32 + 2 * ohf + iy] >> (2 * owf + ix)) & 1u);
        acc = fma(bd, W1R[og * 864 + pos * 24 + c * 8 + oj], acc);
      }
      #pragma unroll
      for (int off = 32; off > 0; off >>= 1) acc += __shfl_xor(acc, off);
      float cur = (float)(acc * 0.25);
      if (lane == src) {
        uint32_t m = 1u << ocb;
        wA = (cur > 1.0f) ? (wA | m) : (wA & ~m);
        wB = (cur > 2.0f) ? (wB | m) : (wB & ~m);
        wF &= wF - 1;
      }
      flagged = __ballot(wF != 0);
    }

    if (wvalid) {
      uint32_t idx = (uint32_t)(tb * 196 + pw);
      A1w[idx] = wA;
      B1w[idx] = wB;
    }
  }
}

// --- LIF1 scan (unchanged) -------------------------------------------------
__global__ __launch_bounds__(64) void scan1(const uint32_t* __restrict__ A1w,
                                            const uint32_t* __restrict__ B1w,
                                            uint32_t* __restrict__ mask1) {
  int chain = blockIdx.x * 64 + threadIdx.x;
  if (chain >= NB * 196) return;
  int b = chain / 196, p = chain % 196;
  const size_t stride = (size_t)NB * 196;
  size_t base = (size_t)b * 196 + p;
  uint32_t prev = 0;
  #pragma unroll
  for (int seg = 0; seg < 4; ++seg) {
    uint32_t Abuf[25], Bbuf[25];
    size_t sb = base + (size_t)(seg * 25) * stride;
    #pragma unroll
    for (int i = 0; i < 25; ++i) {
      Abuf[i] = A1w[sb + i * stride];
      Bbuf[i] = B1w[sb + i * stride];
    }
    #pragma unroll
    for (int i = 0; i < 25; ++i) {
      uint32_t s = (Abuf[i] & ~prev) | (Bbuf[i] & prev);
      mask1[sb + i * stride] = s;
      prev = s;
    }
  }
}

// --- conv2 epilogue helper: ballots + cooperative f64 fix + store ---------
__device__ __forceinline__ void conv2_epilog(const f32x4* ACC, int TBV,
                                             const uint32_t* SW,
                                             const float* epsv,
                                             const double* __restrict__ W2R,
                                             uint32_t* __restrict__ A2w,
                                             uint32_t* __restrict__ B2w,
                                             int lane) {
  const int w = lane;
  const int pw = w >> 1, hfw = w & 1;
  #pragma unroll
  for (int mt2 = 0; mt2 < 2; ++mt2) {
    const int pt = pw - mt2 * 16;
    const bool wvalid = (w < 50) && (pt >= 0) && (pt < 16) && (pw < 25);
    const int qw = (pt & 15) >> 2, rw = pt & 3;
    uint32_t wA = 0, wB = 0, wF = 0;
    #pragma unroll
    for (int nt = 0; nt < 4; ++nt) {
      unsigned long long bA[4], bB[4], bF[4];
      #pragma unroll
      for (int reg = 0; reg < 4; ++reg) {
        float c = ACC[mt2 * 4 + nt][reg] * 0.25f;
        float e = epsv[nt];
        bA[reg] = __ballot(c > 1.0f);
        bB[reg] = __ballot(c > 2.0f);
        bF[reg] = __ballot(fabsf(c - 1.0f) <= e || fabsf(c - 2.0f) <= e);
      }
      if (wvalid && (nt >> 1) == hfw) {
        const int sh = (nt & 1) * 16;
        unsigned long long sA = rw == 0 ? bA[0] : rw == 1 ? bA[1] : rw == 2 ? bA[2] : bA[3];
        unsigned long long sB = rw == 0 ? bB[0] : rw == 1 ? bB[1] : rw == 2 ? bB[2] : bB[3];
        unsigned long long sF = rw == 0 ? bF[0] : rw == 1 ? bF[1] : rw == 2 ? bF[2] : bF[3];
        wA |= (uint32_t)((sA >> (qw * 16)) & 0xffffull) << sh;
        wB |= (uint32_t)((sB >> (qw * 16)) & 0xffffull) << sh;
        wF |= (uint32_t)((sF >> (qw * 16)) & 0xffffull) << sh;
      }
    }

    // wave-cooperative exact f64 fix of flagged bits (rare)
    unsigned long long flagged = __ballot(wF != 0);
    while (flagged) {
      int src = (int)__ffsll(flagged) - 1;
      uint32_t fsrc = (uint32_t)__shfl((int)wF, src);
      int bit = __ffs((int)fsrc) - 1;
      int psrc = src >> 1, hfs = src & 1;
      int oc = hfs * 32 + bit;
      int ohf = psrc / 5, owf = psrc % 5;
      int og = oc >> 4, oj = oc & 15;
      double acc = 0.0;
      for (int t = lane; t < 1152; t += 64) {  // t = c*36 + pos
        int c = t / 36, pos = t - c * 36;
        int iy = pos / 6, ix = pos - iy * 6;
        uint32_t mm = SW[(2 * ohf + iy) * 14 + 2 * owf + ix];
        acc = fma((double)((mm >> c) & 1u),
                  W2R[og * 18432 + c * 576 + pos * 16 + oj], acc);
      }
      #pragma unroll
      for (int off = 32; off > 0; off >>= 1) acc += __shfl_xor(acc, off);
      float cur = (float)(acc * 0.25);
      if (lane == src) {
        uint32_t m = 1u << bit;
        wA = (cur > 1.0f) ? (wA | m) : (wA & ~m);
        wB = (cur > 2.0f) ? (wB | m) : (wB & ~m);
        wF &= wF - 1;
      }
      flagged = __ballot(wF != 0);
    }

    if (wvalid) {
      uint32_t idx = (uint32_t)(TBV * 25 + pw) * 2 + hfw;
      A2w[idx] = wA;
      B2w[idx] = wB;
    }
  }
}

// --- conv2 via MFMA: 2 tb per wave (r15 core) -----------------------------
__global__ __launch_bounds__(256, 3) void conv2_mfma(const uint32_t* __restrict__ mask1,
                                                     const uint16_t* __restrict__ WB,
                                                     const float* __restrict__ EPS,
                                                     const double* __restrict__ W2R,
                                                     uint32_t* __restrict__ A2w,
                                                     uint32_t* __restrict__ B2w) {
  __shared__ uint32_t sM[8 * 196];
  const int tid = threadIdx.x;
  const int wid = tid >> 6, lane = tid & 63;
  const int tb0 = blockIdx.x * 8 + wid * 2;

  for (int i = lane; i < 392; i += 64)
    sM[wid * 392 + i] = mask1[(size_t)tb0 * 196 + i];

  const int q  = lane >> 4;
  const int ln = lane & 15;
  float epsv[4];
  #pragma unroll
  for (int nt = 0; nt < 4; ++nt) epsv[nt] = EPS[32 + nt * 16 + ln];

  const int p0 = ln;
  const int p1 = 16 + ln;
  const bool v1 = (p1 < 25);
  const int oh0 = p0 / 5, ow0 = p0 % 5;
  const int p1c = v1 ? p1 : 0;
  const int oh1 = p1c / 5, ow1 = p1c % 5;

  f32x4 accA[8], accB[8];
  #pragma unroll
  for (int i = 0; i < 8; ++i) { accA[i] = (f32x4)(0.0f); accB[i] = (f32x4)(0.0f); }

  const uint32_t* sW0 = &sM[wid * 392];
  const uint32_t* sW1 = sW0 + 196;

  for (int iy = 0; iy < 6; ++iy) {
    #pragma unroll
    for (int ix = 0; ix < 6; ++ix) {
      const int pos = iy * 6 + ix;
      const int o0 = (2 * oh0 + iy) * 14 + 2 * ow0 + ix;
      const int o1 = (2 * oh1 + iy) * 14 + 2 * ow1 + ix;
      uint32_t w00 = sW0[o0];
      uint32_t w01 = v1 ? sW0[o1] : 0u;
      uint32_t w10 = sW1[o0];
      uint32_t w11 = v1 ? sW1[o1] : 0u;
      uint32_t b00 = (w00 >> (q * 8)) & 0xffu;
      uint32_t b01 = (w01 >> (q * 8)) & 0xffu;
      uint32_t b10 = (w10 >> (q * 8)) & 0xffu;
      uint32_t b11 = (w11 >> (q * 8)) & 0xffu;
      union { uint32_t u[4]; bf16x8 v; } a00, a01, a10, a11;
      #pragma unroll
      for (int i = 0; i < 4; ++i) {
        a00.u[i] = (((b00 >> (2 * i)) & 1u) ? 0x3F80u : 0u) |
                   (((b00 >> (2 * i + 1)) & 1u) ? 0x3F800000u : 0u);
        a01.u[i] = (((b01 >> (2 * i)) & 1u) ? 0x3F80u : 0u) |
                   (((b01 >> (2 * i + 1)) & 1u) ? 0x3F800000u : 0u);
        a10.u[i] = (((b10 >> (2 * i)) & 1u) ? 0x3F80u : 0u) |
                   (((b10 >> (2 * i + 1)) & 1u) ? 0x3F800000u : 0u);
        a11.u[i] = (((b11 >> (2 * i)) & 1u) ? 0x3F80u : 0u) |
                   (((b11 >> (2 * i + 1)) & 1u) ? 0x3F800000u : 0u);
      }
      const uint16_t* bhi_base = WB + (size_t)pos * 2048 + lane * 8;
      const uint16_t* blo_base = bhi_base + 73728;
      #pragma unroll
      for (int nt = 0; nt < 4; ++nt) {
        bf16x8 bhi = *(const bf16x8*)(bhi_base + nt * 512);
        bf16x8 blo = *(const bf16x8*)(blo_base + nt * 512);
        accA[nt] = __builtin_amdgcn_mfma_f32_16x16x32_bf16(a00.v, bhi, accA[nt], 0, 0, 0);
        accA[nt] = __builtin_amdgcn_mfma_f32_16x16x32_bf16(a00.v, blo, accA[nt], 0, 0, 0);
        accA[4 + nt] = __builtin_amdgcn_mfma_f32_16x16x32_bf16(a01.v, bhi, accA[4 + nt], 0, 0, 0);
        accA[4 + nt] = __builtin_amdgcn_mfma_f32_16x16x32_bf16(a01.v, blo, accA[4 + nt], 0, 0, 0);
        accB[nt] = __builtin_amdgcn_mfma_f32_16x16x32_bf16(a10.v, bhi, accB[nt], 0, 0, 0);
        accB[nt] = __builtin_amdgcn_mfma_f32_16x16x32_bf16(a10.v, blo, accB[nt], 0, 0, 0);
        accB[4 + nt] = __builtin_amdgcn_mfma_f32_16x16x32_bf16(a11.v, bhi, accB[4 + nt], 0, 0, 0);
        accB[4 + nt] = __builtin_amdgcn_mfma_f32_16x16x32_bf16(a11.v, blo, accB[4 + nt], 0, 0, 0);
      }
    }
  }

  conv2_epilog(accA, tb0,     sW0, epsv, W2R, A2w, B2w, lane);
  conv2_epilog(accB, tb0 + 1, sW1, epsv, W2R, A2w, B2w, lane);
}

// --- LIF2 scan (unchanged) -------------------------------------------------
__global__ __launch_bounds__(64) void scan2(const uint64_t* __restrict__ A2q,
                                            const uint64_t* __restrict__ B2q,
                                            uint64_t* __restrict__ mask2) {
  int chain = blockIdx.x * 64 + threadIdx.x;
  if (chain >= NB * 25) return;
  int b = chain / 25, p = chain % 25;
  const size_t stride = (size_t)NB * 25;
  size_t base = (size_t)b * 25 + p;
  uint64_t prev = 0;
  #pragma unroll
  for (int seg = 0; seg < 4; ++seg) {
    uint64_t Abuf[25], Bbuf[25];
    size_t sb = base + (size_t)(seg * 25) * stride;
    #pragma unroll
    for (int i = 0; i < 25; ++i) {
      Abuf[i] = A2q[sb + i * stride];
      Bbuf[i] = B2q[sb + i * stride];
    }
    #pragma unroll
    for (int i = 0; i < 25; ++i) {
      uint64_t s = (Abuf[i] & ~prev) | (Bbuf[i] & prev);
      mask2[sb + i * stride] = s;
      prev = s;
    }
  }
}

// --- FC (unchanged) --------------------------------------------------------
__global__ __launch_bounds__(256) void fc_kernel(const uint64_t* __restrict__ mask2,
                                                 const float* __restrict__ W2,
                                                 float* __restrict__ cur3) {
  int gid = blockIdx.x * 256 + threadIdx.x;
  if (gid >= NSTEPS * NB * 80) return;
  int tb = gid / 80, r = gid % 80;
  int o = r >> 3, s = r & 7;
  const uint64_t* m = mask2 + (size_t)tb * 25;
  const float* w = W2 + o * 1600 + s * 200;

  uint64_t mw[25];
  #pragma unroll
  for (int p = 0; p < 25; ++p) mw[p] = m[p];

  const int oc0 = s * 8;
  double acc0 = 0.0, acc1 = 0.0;
  #pragma unroll
  for (int j = 0; j < 8; ++j) {
    const float* wj = w + j * 25;
    double a = 0.0;
    #pragma unroll
    for (int p = 0; p < 25; ++p) {
      double bd = (double)((mw[p] >> (oc0 + j)) & 1ull);
      a = fma(bd, (double)wj[p], a);
    }
    if (j & 1) acc1 += a; else acc0 += a;
  }
  double acc = acc0 + acc1;
  acc += __shfl_xor(acc, 4);
  acc += __shfl_xor(acc, 2);
  acc += __shfl_xor(acc, 1);
  if (s == 0) cur3[tb * 10 + o] = (float)acc;
}

// --- LIF3 (unchanged) ------------------------------------------------------
__global__ __launch_bounds__(64) void lif3_kernel(const float* __restrict__ cur3,
                                                  float* __restrict__ out) {
  int bo = blockIdx.x * 64 + threadIdx.x;
  if (bo >= NB * 10) return;
  float prev = 0.0f;
  #pragma unroll
  for (int seg = 0; seg < 4; ++seg) {
    float cbuf[25];
    #pragma unroll
    for (int i = 0; i < 25; ++i) cbuf[i] = cur3[(seg * 25 + i) * 640 + bo];
    #pragma unroll
    for (int i = 0; i < 25; ++i) {
      int t = seg * 25 + i;
      float mem = cbuf[i] - prev;
      bool s = mem > 1.0f;
      out[t * 640 + bo] = s ? 1.0f : 0.0f;
      out[NSTEPS * 640 + t * 640 + bo] = mem;
      prev = s ? 1.0f : 0.0f;
    }
  }
}

extern "C" void kernel_launch(void* const* d_in, const int* in_sizes, int n_in,
                              void* d_out, int out_size, void* d_ws, size_t ws_size,
                              hipStream_t stream) {
  const float* x    = (const float*)d_in[0];
  const float* W_in = (const float*)d_in[1];
  const float* W_h1 = (const float*)d_in[2];
  const float* W_h2 = (const float*)d_in[3];
  float* out = (float*)d_out;

  unsigned char* ws = (unsigned char*)d_ws;
  double*   W1R   = (double*)(ws + 0);              //     27,648
  double*   W2R   = (double*)(ws + 27648);          //    589,824
  uint16_t* WB1   = (uint16_t*)(ws + 617472);       //     32,768
  uint16_t* WB2   = (uint16_t*)(ws + 650240);       //    294,912
  float*    EPS   = (float*)(ws + 945152);          //        384
  uint32_t* rowm  = (uint32_t*)(ws + 945664);       //  2,457,600
  uint32_t* A1w   = (uint32_t*)(ws + 3403264);      //  5,017,600
  uint32_t* B1w   = (uint32_t*)(ws + 8420864);      //  5,017,600
  uint32_t* mask1 = (uint32_t*)(ws + 13438464);     //  5,017,600
  uint32_t* A2w   = (uint32_t*)(ws + 18456064);     //  1,280,000
  uint32_t* B2w   = (uint32_t*)(ws + 19736064);     //  1,280,000
  uint64_t* mask2 = (uint64_t*)(ws + 21016064);     //  1,280,000
  float*    cur3  = (float*)(ws + 22296064);        //    256,000 (end ~22.6 MB)

  prep_gen<<<678 + 76800, 256, 0, stream>>>(W_in, W_h1, x, W1R, W2R, WB1, WB2,
                                            EPS, rowm);
  conv1_mfma<<<1600, 256, 0, stream>>>(rowm, WB1, EPS, W1R, A1w, B1w);
  scan1<<<(NB * 196 + 63) / 64, 64, 0, stream>>>(A1w, B1w, mask1);
  conv2_mfma<<<800, 256, 0, stream>>>(mask1, WB2, EPS, W2R, A2w, B2w);
  scan2<<<(NB * 25 + 63) / 64, 64, 0, stream>>>((const uint64_t*)A2w,
                                                (const uint64_t*)B2w, mask2);
  fc_kernel<<<(NSTEPS * NB * 80 + 255) / 256, 256, 0, stream>>>(mask2, W_h2, cur3);
  lif3_kernel<<<10, 64, 0, stream>>>(cur3, out);
}